// Round 6
// baseline (296.791 us; speedup 1.0000x reference)
//
#include <hip/hip_runtime.h>

typedef unsigned short u16;
typedef unsigned int u32;
typedef __attribute__((ext_vector_type(8))) short bf16x8;
typedef __attribute__((ext_vector_type(4))) float f32x4;
typedef __attribute__((ext_vector_type(2))) float f32x2;

__device__ __forceinline__ float bf(u16 u){ return __uint_as_float(((u32)u) << 16); }
__device__ __forceinline__ float bf_lo(u32 u){ return __uint_as_float(u << 16); }
__device__ __forceinline__ float bf_hi(u32 u){ return __uint_as_float(u & 0xFFFF0000u); }
__device__ __forceinline__ u16 to_bf16(float f){
    u32 x = __float_as_uint(f);
    u32 r = (x + 0x7FFFu + ((x >> 16) & 1u)) >> 16;
    return (u16)r;
}
__device__ __forceinline__ float leaky(float v){ return (v >= 0.f) ? v : 0.2f * v; }
__device__ __forceinline__ float eexp(float v){
    return __expf(fminf(leaky(v), 80.f));
}
__device__ __forceinline__ f32x2 unpk2(u32 u){
    return (f32x2){bf_lo(u), bf_hi(u)};
}
__device__ __forceinline__ float ldany(const void* p, int i, int fl){
    return fl ? bf(((const u16*)p)[i]) : ((const float*)p)[i];
}
__device__ __forceinline__ u16 ldany_bf(const void* p, int i, int fl){
    return fl ? ((const u16*)p)[i] : to_bf16(((const float*)p)[i]);
}

constexpr int NS = 256;      // edge slices (histogram/scatter blocks)
// bins: 512 dst nodes per bin (shift 9); NBIN = ceil(N/512) <= 128 for N <= 65536

// ========== k1: per-slice LDS histogram (no global atomics) + input conversion ==========
struct HistCvtArgs {
    const int* dst; const int* src; int E; int chE; u16* cnt; int NBIN;
    const void* xin; u16* Xb; int nx;
    const void* W1; const void* W2; u16* W1t; u16* W2t;
    const void* vin[6]; float* vout[6];
    int* flag;
};
__global__ __launch_bounds__(256) void hist_cvt(HistCvtArgs a){
    int b = blockIdx.x;
    if (b < NS){
        __shared__ u32 hist[128];
        if (threadIdx.x < 128) hist[threadIdx.x] = 0;
        __syncthreads();
        int s0 = b * a.chE, s1 = min(a.E, s0 + a.chE);
        for (int i = s0 + threadIdx.x; i < s1; i += 256){
            int d = a.dst[i];
            if (a.src[i] != d) atomicAdd(&hist[d >> 9], 1);
        }
        __syncthreads();
        // bin-major storage: cnt[bin*NS + slice]
        if (threadIdx.x < a.NBIN)
            a.cnt[threadIdx.x * NS + b] = (u16)hist[threadIdx.x];
        return;
    }
    __shared__ int sflag;
    const u16* x16 = (const u16*)a.xin;
    if (threadIdx.x < 64){
        int ok = 1;
        for (int i = threadIdx.x; i < 256; i += 64){
            u16 v = x16[i];
            int e = (v >> 7) & 0xFF;
            if (!((e >= 100 && e <= 140) || (v & 0x7FFFu) == 0)) ok = 0;
        }
        unsigned long long bl = __ballot(ok);
        if (threadIdx.x == 0) sflag = (__popcll(bl) >= 62) ? 1 : 0;
    }
    __syncthreads();
    int fl = sflag;
    int ci = (b - NS) * 256 + threadIdx.x;
    if (ci == 0) *a.flag = fl;
    if (ci < a.nx){ a.Xb[ci] = ldany_bf(a.xin, ci, fl); return; }
    ci -= a.nx;
    if (ci < 128 * 128){
        int n = ci >> 7, k = ci & 127;
        a.W1t[ci] = ldany_bf(a.W1, k * 128 + n, fl);
        return;
    }
    ci -= 128 * 128;
    if (ci < 64 * 128){
        int n = ci >> 7, k = ci & 127;
        a.W2t[ci] = ldany_bf(a.W2, k * 64 + n, fl);
        return;
    }
    ci -= 64 * 128;
    const int vsz[6] = {128, 128, 128, 64, 64, 64};
    #pragma unroll
    for (int s = 0; s < 6; s++){
        if (ci < vsz[s]){ a.vout[s][ci] = ldany(a.vin[s], ci, fl); return; }
        ci -= vsz[s];
    }
}

// ==== k3: per-slice bucket scatter (inline 2D prefix scan) + MFMA GEMM1 + fused logits ====
struct BucketGemmArgs {
    const int* dst; const int* src; int E; int chE; const u16* cnt; int NBIN;
    u32* Sbin;          // [NBIN+1] bin bases (written by scatter block 0)
    u32* bucket;
    const u16* Xb; const u16* W1t; u16* HB;
    const float* a_s; const float* a_d; float* al_s; float* al_d;
    int N;
};
__global__ __launch_bounds__(256) void bucket_gemm(BucketGemmArgs a){
    int b = blockIdx.x;
    if (b < NS){
        __shared__ u32 cur[128];
        __shared__ u32 Tl[129];
        int t = threadIdx.x;
        if (t < a.NBIN){
            const u16* row = a.cnt + (size_t)t * NS;
            u32 cb = 0, tot = 0;
            for (int sx = 0; sx < NS; sx++){
                u32 v = row[sx];
                tot += v;
                cb += (sx < b) ? v : 0u;
            }
            Tl[t + 1] = tot;        // shifted; exclusive prefix below
            cur[t] = cb;            // within-bin offset of this slice
        }
        __syncthreads();
        if (t == 0){
            u32 run = 0;
            Tl[0] = 0;
            for (int g = 1; g <= a.NBIN; g++){ run += Tl[g]; Tl[g] = run; }
        }
        __syncthreads();
        if (t < a.NBIN) cur[t] += Tl[t];              // global slot base
        if (b == 0 && t <= a.NBIN) a.Sbin[t] = Tl[t]; // bin bases for bin_csr
        __syncthreads();
        int s0 = b * a.chE, s1 = min(a.E, s0 + a.chE);
        for (int i = s0 + t; i < s1; i += 256){
            int d = a.dst[i];
            int s = a.src[i];
            if (s != d){
                u32 pos = atomicAdd(&cur[d >> 9], 1);
                a.bucket[pos] = ((u32)d << 16) | (u32)s;
            }
        }
        return;
    }
    int gb = b - NS;
    int lane = threadIdx.x & 63;
    int w = threadIdx.x >> 6;
    int row0 = gb * 64 + w * 16;
    int m = lane & 15, quad = lane >> 4;
    int arow = row0 + m;
    if (arow >= a.N) arow = a.N - 1;
    f32x4 acc[8];
    #pragma unroll
    for (int j = 0; j < 8; j++) acc[j] = (f32x4){0.f, 0.f, 0.f, 0.f};
    const u16* ap = a.Xb + (size_t)arow * 128 + quad * 8;
    const u16* bp = a.W1t + (size_t)m * 128 + quad * 8;
    #pragma unroll
    for (int kc = 0; kc < 4; kc++){
        bf16x8 av = *(const bf16x8*)(ap + kc * 32);
        #pragma unroll
        for (int nb = 0; nb < 8; nb++){
            bf16x8 bv = *(const bf16x8*)(bp + nb * 16 * 128 + kc * 32);
            acc[nb] = __builtin_amdgcn_mfma_f32_16x16x32_bf16(av, bv, acc[nb], 0, 0, 0);
        }
    }
    #pragma unroll
    for (int nb = 0; nb < 8; nb++){
        #pragma unroll
        for (int r = 0; r < 4; r++){
            int grow = row0 + quad * 4 + r;
            if (grow < a.N) a.HB[(size_t)grow * 128 + nb * 16 + m] = to_bf16(acc[nb][r]);
        }
    }
    float asr[8], adr[8];
    #pragma unroll
    for (int nb = 0; nb < 8; nb++){ asr[nb] = a.a_s[nb * 16 + m]; adr[nb] = a.a_d[nb * 16 + m]; }
    #pragma unroll
    for (int r = 0; r < 4; r++){
        int grow = row0 + quad * 4 + r;
        #pragma unroll
        for (int h = 0; h < 4; h++){
            float ps = acc[2 * h][r] * asr[2 * h] + acc[2 * h + 1][r] * asr[2 * h + 1];
            float pd = acc[2 * h][r] * adr[2 * h] + acc[2 * h + 1][r] * adr[2 * h + 1];
            #pragma unroll
            for (int d = 1; d < 16; d <<= 1){
                ps += __shfl_xor(ps, d);
                pd += __shfl_xor(pd, d);
            }
            if (m == h && grow < a.N){
                a.al_s[grow * 4 + h] = ps;
                a.al_d[grow * 4 + h] = pd;
            }
        }
    }
}

// ==== k4: per-bin CSR finalize — LDS degree count + scan, coalesced off, L2-local csr ====
__global__ __launch_bounds__(256) void bin_csr(const u32* __restrict__ Sbin,
                                               const u32* __restrict__ bucket,
                                               int* __restrict__ off,
                                               u16* __restrict__ csr,
                                               int N, int NBIN){
    __shared__ u32 degL[512];
    __shared__ u32 curL[512];
    __shared__ int wsum[4];
    int b = blockIdx.x, t = threadIdx.x;
    int lo = b << 9;
    u32 base = Sbin[b];
    u32 end  = Sbin[b + 1];
    degL[t] = 0; degL[t + 256] = 0;
    __syncthreads();
    for (u32 i = base + t; i < end; i += 256){
        u32 pr = bucket[i];
        atomicAdd(&degL[(pr >> 16) - lo], 1);
    }
    __syncthreads();
    u32 d0 = degL[2 * t], d1 = degL[2 * t + 1];
    int p = (int)(d0 + d1);
    int v = p;
    #pragma unroll
    for (int d = 1; d < 64; d <<= 1){
        int o = __shfl_up(v, d);
        if ((t & 63) >= d) v += o;
    }
    if ((t & 63) == 63) wsum[t >> 6] = v;
    __syncthreads();
    int woff = 0;
    for (int wv = 0; wv < (t >> 6); wv++) woff += wsum[wv];
    int eb = woff + v - p;
    curL[2 * t] = eb;
    curL[2 * t + 1] = eb + d0;
    int n0 = lo + 2 * t, n1 = lo + 2 * t + 1;
    if (n0 < N) off[n0] = (int)(base + eb);
    if (n1 < N) off[n1] = (int)(base + eb + d0);
    if (b == NBIN - 1 && t == 255) off[N] = (int)end;
    __syncthreads();
    for (u32 i = base + t; i < end; i += 256){
        u32 pr = bucket[i];
        u32 pos = base + atomicAdd(&curL[(pr >> 16) - lo], 1);
        csr[pos] = (u16)(pr & 0xFFFF);
    }
}

// ------- fused layer-1 aggregate + per-wave MFMA GEMM2 + layer-2 logits -------
// Round-3 aggregation structure EXACTLY (4 nodes/block, ONE node per wave, no
// barrier). After the full-wave butterfly every lane holds the complete reduced
// h_mid row; each wave then runs its own 1x128 @ 128x64 GEMM2 as an MFMA tail:
// A-frag row 0 = h_mid (16 intra-wave shfl broadcasts of packed bf16 words),
// rows 1-15 = 0; B = W2t (L1-resident). Row 0 of D = h2 row + fused logits.
// No __syncthreads, no LDS, no wave coupling — kills gemm2_logits kernel and
// the 25.6 MB hmidb HBM round-trip.
__global__ __launch_bounds__(256) void agg1_gemm2(const int* __restrict__ off,
                                                  const u16* __restrict__ csr,
                                                  const u16* __restrict__ h1,
                                                  const float* __restrict__ als,
                                                  const float* __restrict__ ald,
                                                  const float* __restrict__ b1,
                                                  const u16* __restrict__ W2t,
                                                  const float* __restrict__ as2,
                                                  const float* __restrict__ ad2,
                                                  u16* __restrict__ h2b,
                                                  float* __restrict__ als2,
                                                  float* __restrict__ ald2,
                                                  int N){
    int lane = threadIdx.x & 63;
    int n = blockIdx.x * 4 + (threadIdx.x >> 6);
    if (n >= N) return;
    int o0 = off[n], o1 = off[n + 1];
    int q = lane >> 4, ql = lane & 15;   // q: edge slot (mod 4), ql: column group
    int c0 = ql * 8;
    int head = ql >> 2;
    float aldh = ald[n * 4 + head];
    f32x2 a0 = {0.f, 0.f}, a1 = {0.f, 0.f}, a2 = {0.f, 0.f}, a3 = {0.f, 0.f};
    float s = 0.f;
    int j = o0 + q;
    for (; j + 12 < o1; j += 16){
        int sc0 = csr[j], sc1 = csr[j + 4], sc2 = csr[j + 8], sc3 = csr[j + 12];
        float e0 = eexp(als[sc0 * 4 + head] + aldh);
        float e1 = eexp(als[sc1 * 4 + head] + aldh);
        float e2 = eexp(als[sc2 * 4 + head] + aldh);
        float e3 = eexp(als[sc3 * 4 + head] + aldh);
        uint4 u0 = *(const uint4*)&h1[(size_t)sc0 * 128 + c0];
        uint4 u1 = *(const uint4*)&h1[(size_t)sc1 * 128 + c0];
        uint4 u2 = *(const uint4*)&h1[(size_t)sc2 * 128 + c0];
        uint4 u3 = *(const uint4*)&h1[(size_t)sc3 * 128 + c0];
        s += (e0 + e1) + (e2 + e3);
        f32x2 ev0 = {e0, e0}, ev1 = {e1, e1}, ev2 = {e2, e2}, ev3 = {e3, e3};
        a0 += ev0 * unpk2(u0.x); a1 += ev0 * unpk2(u0.y);
        a2 += ev0 * unpk2(u0.z); a3 += ev0 * unpk2(u0.w);
        a0 += ev1 * unpk2(u1.x); a1 += ev1 * unpk2(u1.y);
        a2 += ev1 * unpk2(u1.z); a3 += ev1 * unpk2(u1.w);
        a0 += ev2 * unpk2(u2.x); a1 += ev2 * unpk2(u2.y);
        a2 += ev2 * unpk2(u2.z); a3 += ev2 * unpk2(u2.w);
        a0 += ev3 * unpk2(u3.x); a1 += ev3 * unpk2(u3.y);
        a2 += ev3 * unpk2(u3.z); a3 += ev3 * unpk2(u3.w);
    }
    for (; j < o1; j += 4){
        int sc = csr[j];
        float e = eexp(als[sc * 4 + head] + aldh);
        uint4 u = *(const uint4*)&h1[(size_t)sc * 128 + c0];
        s += e;
        f32x2 ev = {e, e};
        a0 += ev * unpk2(u.x); a1 += ev * unpk2(u.y);
        a2 += ev * unpk2(u.z); a3 += ev * unpk2(u.w);
    }
    float acc[8] = {a0.x, a0.y, a1.x, a1.y, a2.x, a2.y, a3.x, a3.y};
    // full-wave butterfly: every lane gets its column-group's reduced values
    s += __shfl_xor(s, 16);
    s += __shfl_xor(s, 32);
    #pragma unroll
    for (int i = 0; i < 8; i++){
        acc[i] += __shfl_xor(acc[i], 16);
        acc[i] += __shfl_xor(acc[i], 32);
    }
    // epilogue on ALL lanes (bit-identical to round-3 q==0 path)
    float esx = eexp(als[n * 4 + head] + aldh);
    float inv = 1.f / (s + esx + 1e-16f);
    uint4 u = *(const uint4*)&h1[(size_t)n * 128 + c0];
    acc[0] += esx * bf_lo(u.x); acc[1] += esx * bf_hi(u.x);
    acc[2] += esx * bf_lo(u.y); acc[3] += esx * bf_hi(u.y);
    acc[4] += esx * bf_lo(u.z); acc[5] += esx * bf_hi(u.z);
    acc[6] += esx * bf_lo(u.w); acc[7] += esx * bf_hi(u.w);
    float4 bA = *(const float4*)&b1[c0];
    float4 bB = *(const float4*)&b1[c0 + 4];
    u16 pk[8];
    pk[0] = to_bf16(fmaxf(acc[0] * inv + bA.x, 0.f));
    pk[1] = to_bf16(fmaxf(acc[1] * inv + bA.y, 0.f));
    pk[2] = to_bf16(fmaxf(acc[2] * inv + bA.z, 0.f));
    pk[3] = to_bf16(fmaxf(acc[3] * inv + bA.w, 0.f));
    pk[4] = to_bf16(fmaxf(acc[4] * inv + bB.x, 0.f));
    pk[5] = to_bf16(fmaxf(acc[5] * inv + bB.y, 0.f));
    pk[6] = to_bf16(fmaxf(acc[6] * inv + bB.z, 0.f));
    pk[7] = to_bf16(fmaxf(acc[7] * inv + bB.w, 0.f));
    u32 pkw0 = (u32)pk[0] | ((u32)pk[1] << 16);
    u32 pkw1 = (u32)pk[2] | ((u32)pk[3] << 16);
    u32 pkw2 = (u32)pk[4] | ((u32)pk[5] << 16);
    u32 pkw3 = (u32)pk[6] | ((u32)pk[7] << 16);
    // ---- per-wave GEMM2 tail: D(16x16 x4) = A(row0=h_mid) * W2t, no barrier ----
    int m = ql, quad = q;
    f32x4 acc2[4];
    #pragma unroll
    for (int z = 0; z < 4; z++) acc2[z] = (f32x4){0.f, 0.f, 0.f, 0.f};
    const u16* bp = W2t + (size_t)m * 128 + quad * 8;
    #pragma unroll
    for (int kc = 0; kc < 4; kc++){
        int srcl = kc * 4 + quad;   // lane holding cols kc*32+quad*8 .. +7
        union { u32 w[4]; bf16x8 v; } au;
        au.w[0] = (u32)__shfl((int)pkw0, srcl);
        au.w[1] = (u32)__shfl((int)pkw1, srcl);
        au.w[2] = (u32)__shfl((int)pkw2, srcl);
        au.w[3] = (u32)__shfl((int)pkw3, srcl);
        if (m != 0){ au.w[0] = 0; au.w[1] = 0; au.w[2] = 0; au.w[3] = 0; }
        #pragma unroll
        for (int nb = 0; nb < 4; nb++){
            bf16x8 bv = *(const bf16x8*)(bp + nb * 16 * 128 + kc * 32);
            acc2[nb] = __builtin_amdgcn_mfma_f32_16x16x32_bf16(au.v, bv, acc2[nb], 0, 0, 0);
        }
    }
    // row 0 of D (quad==0, r==0) = this node's h2 row; other rows are zero
    float hv0 = acc2[0][0], hv1 = acc2[1][0], hv2 = acc2[2][0], hv3 = acc2[3][0];
    if (quad == 0){
        h2b[(size_t)n * 64 +  0 + m] = to_bf16(hv0);
        h2b[(size_t)n * 64 + 16 + m] = to_bf16(hv1);
        h2b[(size_t)n * 64 + 32 + m] = to_bf16(hv2);
        h2b[(size_t)n * 64 + 48 + m] = to_bf16(hv3);
    }
    float ps = 0.f, pd = 0.f;
    if (quad == 0){
        ps = hv0 * as2[m] + hv1 * as2[16 + m] + hv2 * as2[32 + m] + hv3 * as2[48 + m];
        pd = hv0 * ad2[m] + hv1 * ad2[16 + m] + hv2 * ad2[32 + m] + hv3 * ad2[48 + m];
    }
    #pragma unroll
    for (int d = 1; d < 64; d <<= 1){
        ps += __shfl_xor(ps, d);
        pd += __shfl_xor(pd, d);
    }
    if (lane == 0){
        als2[n] = ps;
        ald2[n] = pd;
    }
}

// ------- layer-2 aggregate: single pass, pk-f32x2 accum -------
__global__ __launch_bounds__(256) void gat_agg2(const int* __restrict__ off,
                                                const u16* __restrict__ csr,
                                                const u16* __restrict__ h2,
                                                const float* __restrict__ als,
                                                const float* __restrict__ ald,
                                                const float* __restrict__ b2,
                                                void* __restrict__ outv, int N,
                                                const int* __restrict__ flag){
    int lane = threadIdx.x & 63;
    int n = blockIdx.x * 4 + (threadIdx.x >> 6);
    if (n >= N) return;
    int o0 = off[n], o1 = off[n + 1];
    int oc = lane >> 3, ol = lane & 7;   // oc: edge slot (mod 8), ol: column group
    int c0 = ol * 8;
    float aldn = ald[n];
    f32x2 a0 = {0.f, 0.f}, a1 = {0.f, 0.f}, a2 = {0.f, 0.f}, a3 = {0.f, 0.f};
    float s = 0.f;
    int j = o0 + oc;
    for (; j + 8 < o1; j += 16){
        int sc0 = csr[j], sc1 = csr[j + 8];
        float e0 = eexp(als[sc0] + aldn);
        float e1 = eexp(als[sc1] + aldn);
        uint4 u0 = *(const uint4*)&h2[(size_t)sc0 * 64 + c0];
        uint4 u1 = *(const uint4*)&h2[(size_t)sc1 * 64 + c0];
        s += e0 + e1;
        f32x2 ev0 = {e0, e0}, ev1 = {e1, e1};
        a0 += ev0 * unpk2(u0.x); a1 += ev0 * unpk2(u0.y);
        a2 += ev0 * unpk2(u0.z); a3 += ev0 * unpk2(u0.w);
        a0 += ev1 * unpk2(u1.x); a1 += ev1 * unpk2(u1.y);
        a2 += ev1 * unpk2(u1.z); a3 += ev1 * unpk2(u1.w);
    }
    if (j < o1){
        int sc = csr[j];
        float e = eexp(als[sc] + aldn);
        uint4 u = *(const uint4*)&h2[(size_t)sc * 64 + c0];
        s += e;
        f32x2 ev = {e, e};
        a0 += ev * unpk2(u.x); a1 += ev * unpk2(u.y);
        a2 += ev * unpk2(u.z); a3 += ev * unpk2(u.w);
    }
    float acc[8] = {a0.x, a0.y, a1.x, a1.y, a2.x, a2.y, a3.x, a3.y};
    // reduce over the 8 edge slots (oc = lane bits 3..5)
    s += __shfl_xor(s, 8);
    s += __shfl_xor(s, 16);
    s += __shfl_xor(s, 32);
    #pragma unroll
    for (int i = 0; i < 8; i++){
        acc[i] += __shfl_xor(acc[i], 8);
        acc[i] += __shfl_xor(acc[i], 16);
        acc[i] += __shfl_xor(acc[i], 32);
    }
    if (oc == 0){
        float esx = eexp(als[n] + aldn);
        float inv = 1.f / (s + esx + 1e-16f);
        uint4 u = *(const uint4*)&h2[(size_t)n * 64 + c0];
        acc[0] += esx * bf_lo(u.x); acc[1] += esx * bf_hi(u.x);
        acc[2] += esx * bf_lo(u.y); acc[3] += esx * bf_hi(u.y);
        acc[4] += esx * bf_lo(u.z); acc[5] += esx * bf_hi(u.z);
        acc[6] += esx * bf_lo(u.w); acc[7] += esx * bf_hi(u.w);
        float4 bA = *(const float4*)&b2[c0];
        float4 bB = *(const float4*)&b2[c0 + 4];
        float r[8];
        r[0] = acc[0] * inv + bA.x; r[1] = acc[1] * inv + bA.y;
        r[2] = acc[2] * inv + bA.z; r[3] = acc[3] * inv + bA.w;
        r[4] = acc[4] * inv + bB.x; r[5] = acc[5] * inv + bB.y;
        r[6] = acc[6] * inv + bB.z; r[7] = acc[7] * inv + bB.w;
        if (*flag){
            u16 pk[8];
            #pragma unroll
            for (int i = 0; i < 8; i++) pk[i] = to_bf16(r[i]);
            *(uint4*)&((u16*)outv)[(size_t)n * 64 + c0] = *(uint4*)pk;
        } else {
            float* op = &((float*)outv)[(size_t)n * 64 + c0];
            *(float4*)op = make_float4(r[0], r[1], r[2], r[3]);
            *(float4*)(op + 4) = make_float4(r[4], r[5], r[6], r[7]);
        }
    }
}

extern "C" void kernel_launch(void* const* d_in, const int* in_sizes, int n_in,
                              void* d_out, int out_size, void* d_ws, size_t ws_size,
                              hipStream_t stream){
    const int* ei  = (const int*)d_in[1];
    const int N = in_sizes[0] / 128;
    const int E = in_sizes[1] / 2;
    const int* src = ei;
    const int* dst = ei + E;
    const int NBIN = (N + 511) >> 9;         // <=128 while N<=65536
    const int chE  = (E + NS - 1) / NS;

    char* w = (char*)d_ws;
    auto alloc = [&](size_t bytes){ char* p = w; w += (bytes + 255) & ~(size_t)255; return p; };
    int*   flag  = (int*)  alloc(4);
    u16*   cnt   = (u16*)  alloc((size_t)NS * NBIN * 2);
    u32*   Sbin  = (u32*)  alloc((size_t)(NBIN + 1) * 4);
    u32*   bucket= (u32*)  alloc((size_t)E * 4);
    int*   off   = (int*)  alloc((size_t)(N + 1) * 4);
    u16*   csr   = (u16*)  alloc((size_t)E * 2);
    u16*   W1t   = (u16*)  alloc(128 * 128 * 2);
    u16*   W2t   = (u16*)  alloc(64 * 128 * 2);
    float* as1f  = (float*)alloc(128 * 4);
    float* ad1f  = (float*)alloc(128 * 4);
    float* b1f   = (float*)alloc(128 * 4);
    float* as2f  = (float*)alloc(64 * 4);
    float* ad2f  = (float*)alloc(64 * 4);
    float* b2f   = (float*)alloc(64 * 4);
    u16*   Xb    = (u16*)  alloc((size_t)N * 128 * 2);
    u16*   h1b   = (u16*)  alloc((size_t)N * 128 * 2);
    u16*   h2b   = (u16*)  alloc((size_t)N * 64 * 2);
    float* als1  = (float*)alloc((size_t)N * 4 * 4);
    float* ald1  = (float*)alloc((size_t)N * 4 * 4);
    float* als2  = (float*)alloc((size_t)N * 4);   // separate: agg1_gemm2 writes these
    float* ald2  = (float*)alloc((size_t)N * 4);   // while other blocks still read als1/ald1

    HistCvtArgs k1;
    k1.dst = dst; k1.src = src; k1.E = E; k1.chE = chE; k1.cnt = cnt; k1.NBIN = NBIN;
    k1.xin = d_in[0]; k1.Xb = Xb; k1.nx = N * 128;
    k1.W1 = d_in[2]; k1.W2 = d_in[6]; k1.W1t = W1t; k1.W2t = W2t;
    const void* vin[6]  = {d_in[3], d_in[4], d_in[5], d_in[7], d_in[8], d_in[9]};
    float* vout[6] = {as1f, ad1f, b1f, as2f, ad2f, b2f};
    for (int s = 0; s < 6; s++){ k1.vin[s] = vin[s]; k1.vout[s] = vout[s]; }
    k1.flag = flag;
    int cvt_total = N * 128 + 128 * 128 + 64 * 128 + 576;
    hist_cvt<<<NS + (cvt_total + 255) / 256, 256, 0, stream>>>(k1);

    BucketGemmArgs k3;
    k3.dst = dst; k3.src = src; k3.E = E; k3.chE = chE; k3.cnt = cnt; k3.NBIN = NBIN;
    k3.Sbin = Sbin;
    k3.bucket = bucket;
    k3.Xb = Xb; k3.W1t = W1t; k3.HB = h1b;
    k3.a_s = as1f; k3.a_d = ad1f; k3.al_s = als1; k3.al_d = ald1;
    k3.N = N;
    bucket_gemm<<<NS + (N + 63) / 64, 256, 0, stream>>>(k3);

    bin_csr<<<NBIN, 256, 0, stream>>>(Sbin, bucket, off, csr, N, NBIN);

    agg1_gemm2<<<(N + 3) / 4, 256, 0, stream>>>(off, csr, h1b, als1, ald1, b1f,
                                                W2t, as2f, ad2f, h2b, als2, ald2, N);

    gat_agg2<<<(N + 3) / 4, 256, 0, stream>>>(off, csr, h2b, als2, ald2, b2f, d_out, N, flag);
}

// Round 7
// 228.721 us; speedup vs baseline: 1.2976x; 1.2976x over previous
//
#include <hip/hip_runtime.h>

typedef unsigned short u16;
typedef unsigned int u32;
typedef __attribute__((ext_vector_type(8))) short bf16x8;
typedef __attribute__((ext_vector_type(4))) float f32x4;
typedef __attribute__((ext_vector_type(2))) float f32x2;

__device__ __forceinline__ float bf(u16 u){ return __uint_as_float(((u32)u) << 16); }
__device__ __forceinline__ float bf_lo(u32 u){ return __uint_as_float(u << 16); }
__device__ __forceinline__ float bf_hi(u32 u){ return __uint_as_float(u & 0xFFFF0000u); }
__device__ __forceinline__ u16 to_bf16(float f){
    u32 x = __float_as_uint(f);
    u32 r = (x + 0x7FFFu + ((x >> 16) & 1u)) >> 16;
    return (u16)r;
}
__device__ __forceinline__ float leaky(float v){ return (v >= 0.f) ? v : 0.2f * v; }
__device__ __forceinline__ float eexp(float v){
    return __expf(fminf(leaky(v), 80.f));
}
__device__ __forceinline__ f32x2 unpk2(u32 u){
    return (f32x2){bf_lo(u), bf_hi(u)};
}
__device__ __forceinline__ float ldany(const void* p, int i, int fl){
    return fl ? bf(((const u16*)p)[i]) : ((const float*)p)[i];
}
__device__ __forceinline__ u16 ldany_bf(const void* p, int i, int fl){
    return fl ? ((const u16*)p)[i] : to_bf16(((const float*)p)[i]);
}

constexpr int NS = 256;      // edge slices (histogram/scatter blocks)
// bins: 512 dst nodes per bin (shift 9); NBIN = ceil(N/512) <= 128 for N <= 65536

// ========== k1: per-slice LDS histogram (no global atomics) + input conversion ==========
struct HistCvtArgs {
    const int* dst; const int* src; int E; int chE; u16* cnt; int NBIN;
    const void* xin; u16* Xb; int nx;
    const void* W1; const void* W2; u16* W1t; u16* W2t;
    const void* vin[6]; float* vout[6];
    int* flag;
};
__global__ __launch_bounds__(256) void hist_cvt(HistCvtArgs a){
    int b = blockIdx.x;
    if (b < NS){
        __shared__ u32 hist[128];
        if (threadIdx.x < 128) hist[threadIdx.x] = 0;
        __syncthreads();
        int s0 = b * a.chE, s1 = min(a.E, s0 + a.chE);
        for (int i = s0 + threadIdx.x; i < s1; i += 256){
            int d = a.dst[i];
            if (a.src[i] != d) atomicAdd(&hist[d >> 9], 1);
        }
        __syncthreads();
        // bin-major storage: cnt[bin*NS + slice]
        if (threadIdx.x < a.NBIN)
            a.cnt[threadIdx.x * NS + b] = (u16)hist[threadIdx.x];
        return;
    }
    __shared__ int sflag;
    const u16* x16 = (const u16*)a.xin;
    if (threadIdx.x < 64){
        int ok = 1;
        for (int i = threadIdx.x; i < 256; i += 64){
            u16 v = x16[i];
            int e = (v >> 7) & 0xFF;
            if (!((e >= 100 && e <= 140) || (v & 0x7FFFu) == 0)) ok = 0;
        }
        unsigned long long bl = __ballot(ok);
        if (threadIdx.x == 0) sflag = (__popcll(bl) >= 62) ? 1 : 0;
    }
    __syncthreads();
    int fl = sflag;
    int ci = (b - NS) * 256 + threadIdx.x;
    if (ci == 0) *a.flag = fl;
    if (ci < a.nx){ a.Xb[ci] = ldany_bf(a.xin, ci, fl); return; }
    ci -= a.nx;
    if (ci < 128 * 128){
        int n = ci >> 7, k = ci & 127;
        a.W1t[ci] = ldany_bf(a.W1, k * 128 + n, fl);
        return;
    }
    ci -= 128 * 128;
    if (ci < 64 * 128){
        int n = ci >> 7, k = ci & 127;
        a.W2t[ci] = ldany_bf(a.W2, k * 64 + n, fl);
        return;
    }
    ci -= 64 * 128;
    const int vsz[6] = {128, 128, 128, 64, 64, 64};
    #pragma unroll
    for (int s = 0; s < 6; s++){
        if (ci < vsz[s]){ a.vout[s][ci] = ldany(a.vin[s], ci, fl); return; }
        ci -= vsz[s];
    }
}

// ==== k3: per-slice bucket scatter (inline 2D prefix scan) + MFMA GEMM1 + fused logits ====
struct BucketGemmArgs {
    const int* dst; const int* src; int E; int chE; const u16* cnt; int NBIN;
    u32* Sbin;          // [NBIN+1] bin bases (written by scatter block 0)
    u32* bucket;
    const u16* Xb; const u16* W1t; u16* HB;
    const float* a_s; const float* a_d; float* al_s; float* al_d;
    int N;
};
__global__ __launch_bounds__(256) void bucket_gemm(BucketGemmArgs a){
    int b = blockIdx.x;
    if (b < NS){
        __shared__ u32 cur[128];
        __shared__ u32 Tl[129];
        int t = threadIdx.x;
        if (t < a.NBIN){
            const u16* row = a.cnt + (size_t)t * NS;
            u32 cb = 0, tot = 0;
            for (int sx = 0; sx < NS; sx++){
                u32 v = row[sx];
                tot += v;
                cb += (sx < b) ? v : 0u;
            }
            Tl[t + 1] = tot;        // shifted; exclusive prefix below
            cur[t] = cb;            // within-bin offset of this slice
        }
        __syncthreads();
        if (t == 0){
            u32 run = 0;
            Tl[0] = 0;
            for (int g = 1; g <= a.NBIN; g++){ run += Tl[g]; Tl[g] = run; }
        }
        __syncthreads();
        if (t < a.NBIN) cur[t] += Tl[t];              // global slot base
        if (b == 0 && t <= a.NBIN) a.Sbin[t] = Tl[t]; // bin bases for bin_csr
        __syncthreads();
        int s0 = b * a.chE, s1 = min(a.E, s0 + a.chE);
        for (int i = s0 + t; i < s1; i += 256){
            int d = a.dst[i];
            int s = a.src[i];
            if (s != d){
                u32 pos = atomicAdd(&cur[d >> 9], 1);
                a.bucket[pos] = ((u32)d << 16) | (u32)s;
            }
        }
        return;
    }
    int gb = b - NS;
    int lane = threadIdx.x & 63;
    int w = threadIdx.x >> 6;
    int row0 = gb * 64 + w * 16;
    int m = lane & 15, quad = lane >> 4;
    int arow = row0 + m;
    if (arow >= a.N) arow = a.N - 1;
    f32x4 acc[8];
    #pragma unroll
    for (int j = 0; j < 8; j++) acc[j] = (f32x4){0.f, 0.f, 0.f, 0.f};
    const u16* ap = a.Xb + (size_t)arow * 128 + quad * 8;
    const u16* bp = a.W1t + (size_t)m * 128 + quad * 8;
    #pragma unroll
    for (int kc = 0; kc < 4; kc++){
        bf16x8 av = *(const bf16x8*)(ap + kc * 32);
        #pragma unroll
        for (int nb = 0; nb < 8; nb++){
            bf16x8 bv = *(const bf16x8*)(bp + nb * 16 * 128 + kc * 32);
            acc[nb] = __builtin_amdgcn_mfma_f32_16x16x32_bf16(av, bv, acc[nb], 0, 0, 0);
        }
    }
    #pragma unroll
    for (int nb = 0; nb < 8; nb++){
        #pragma unroll
        for (int r = 0; r < 4; r++){
            int grow = row0 + quad * 4 + r;
            if (grow < a.N) a.HB[(size_t)grow * 128 + nb * 16 + m] = to_bf16(acc[nb][r]);
        }
    }
    float asr[8], adr[8];
    #pragma unroll
    for (int nb = 0; nb < 8; nb++){ asr[nb] = a.a_s[nb * 16 + m]; adr[nb] = a.a_d[nb * 16 + m]; }
    #pragma unroll
    for (int r = 0; r < 4; r++){
        int grow = row0 + quad * 4 + r;
        #pragma unroll
        for (int h = 0; h < 4; h++){
            float ps = acc[2 * h][r] * asr[2 * h] + acc[2 * h + 1][r] * asr[2 * h + 1];
            float pd = acc[2 * h][r] * adr[2 * h] + acc[2 * h + 1][r] * adr[2 * h + 1];
            #pragma unroll
            for (int d = 1; d < 16; d <<= 1){
                ps += __shfl_xor(ps, d);
                pd += __shfl_xor(pd, d);
            }
            if (m == h && grow < a.N){
                a.al_s[grow * 4 + h] = ps;
                a.al_d[grow * 4 + h] = pd;
            }
        }
    }
}

// ==== k4: per-bin CSR finalize — LDS degree count + scan, coalesced off, L2-local csr ====
__global__ __launch_bounds__(256) void bin_csr(const u32* __restrict__ Sbin,
                                               const u32* __restrict__ bucket,
                                               int* __restrict__ off,
                                               u16* __restrict__ csr,
                                               int N, int NBIN){
    __shared__ u32 degL[512];
    __shared__ u32 curL[512];
    __shared__ int wsum[4];
    int b = blockIdx.x, t = threadIdx.x;
    int lo = b << 9;
    u32 base = Sbin[b];
    u32 end  = Sbin[b + 1];
    degL[t] = 0; degL[t + 256] = 0;
    __syncthreads();
    for (u32 i = base + t; i < end; i += 256){
        u32 pr = bucket[i];
        atomicAdd(&degL[(pr >> 16) - lo], 1);
    }
    __syncthreads();
    u32 d0 = degL[2 * t], d1 = degL[2 * t + 1];
    int p = (int)(d0 + d1);
    int v = p;
    #pragma unroll
    for (int d = 1; d < 64; d <<= 1){
        int o = __shfl_up(v, d);
        if ((t & 63) >= d) v += o;
    }
    if ((t & 63) == 63) wsum[t >> 6] = v;
    __syncthreads();
    int woff = 0;
    for (int wv = 0; wv < (t >> 6); wv++) woff += wsum[wv];
    int eb = woff + v - p;
    curL[2 * t] = eb;
    curL[2 * t + 1] = eb + d0;
    int n0 = lo + 2 * t, n1 = lo + 2 * t + 1;
    if (n0 < N) off[n0] = (int)(base + eb);
    if (n1 < N) off[n1] = (int)(base + eb + d0);
    if (b == NBIN - 1 && t == 255) off[N] = (int)end;
    __syncthreads();
    for (u32 i = base + t; i < end; i += 256){
        u32 pr = bucket[i];
        u32 pos = base + atomicAdd(&curL[(pr >> 16) - lo], 1);
        csr[pos] = (u16)(pr & 0xFFFF);
    }
}

// ============ GEMM2 (64 cols) with fused logits (H=1) ============
__global__ __launch_bounds__(256) void gemm2_logits(const u16* __restrict__ Xb,
                                                    const u16* __restrict__ Wt,
                                                    u16* __restrict__ HB,
                                                    const float* __restrict__ a_s,
                                                    const float* __restrict__ a_d,
                                                    float* __restrict__ al_s,
                                                    float* __restrict__ al_d, int N){
    int lane = threadIdx.x & 63;
    int w = threadIdx.x >> 6;
    int row0 = blockIdx.x * 64 + w * 16;
    int m = lane & 15, quad = lane >> 4;
    int arow = row0 + m;
    if (arow >= N) arow = N - 1;
    f32x4 acc[4];
    #pragma unroll
    for (int j = 0; j < 4; j++) acc[j] = (f32x4){0.f, 0.f, 0.f, 0.f};
    const u16* ap = Xb + (size_t)arow * 128 + quad * 8;
    const u16* bp = Wt + (size_t)m * 128 + quad * 8;
    #pragma unroll
    for (int kc = 0; kc < 4; kc++){
        bf16x8 av = *(const bf16x8*)(ap + kc * 32);
        #pragma unroll
        for (int nb = 0; nb < 4; nb++){
            bf16x8 bv = *(const bf16x8*)(bp + nb * 16 * 128 + kc * 32);
            acc[nb] = __builtin_amdgcn_mfma_f32_16x16x32_bf16(av, bv, acc[nb], 0, 0, 0);
        }
    }
    #pragma unroll
    for (int nb = 0; nb < 4; nb++){
        #pragma unroll
        for (int r = 0; r < 4; r++){
            int grow = row0 + quad * 4 + r;
            if (grow < N) HB[(size_t)grow * 64 + nb * 16 + m] = to_bf16(acc[nb][r]);
        }
    }
    float asr[4], adr[4];
    #pragma unroll
    for (int nb = 0; nb < 4; nb++){ asr[nb] = a_s[nb * 16 + m]; adr[nb] = a_d[nb * 16 + m]; }
    #pragma unroll
    for (int r = 0; r < 4; r++){
        int grow = row0 + quad * 4 + r;
        float ps = 0.f, pd = 0.f;
        #pragma unroll
        for (int nb = 0; nb < 4; nb++){ ps += acc[nb][r] * asr[nb]; pd += acc[nb][r] * adr[nb]; }
        #pragma unroll
        for (int d = 1; d < 16; d <<= 1){
            ps += __shfl_xor(ps, d);
            pd += __shfl_xor(pd, d);
        }
        if (m == 0 && grow < N){
            al_s[grow] = ps;
            al_d[grow] = pd;
        }
    }
}

// ------- layer-1 aggregate: single pass, pk-f32x2 accum, 4-deep edge pipeline -------
__global__ __launch_bounds__(256) void gat_agg1(const int* __restrict__ off,
                                                const u16* __restrict__ csr,
                                                const u16* __restrict__ h1,
                                                const float* __restrict__ als,
                                                const float* __restrict__ ald,
                                                const float* __restrict__ b1,
                                                u16* __restrict__ outm, int N){
    int lane = threadIdx.x & 63;
    int n = blockIdx.x * 4 + (threadIdx.x >> 6);
    if (n >= N) return;
    int o0 = off[n], o1 = off[n + 1];
    int q = lane >> 4, ql = lane & 15;   // q: edge slot (mod 4), ql: column group
    int c0 = ql * 8;
    int head = ql >> 2;
    float aldh = ald[n * 4 + head];
    f32x2 a0 = {0.f, 0.f}, a1 = {0.f, 0.f}, a2 = {0.f, 0.f}, a3 = {0.f, 0.f};
    float s = 0.f;
    int j = o0 + q;
    for (; j + 12 < o1; j += 16){
        int sc0 = csr[j], sc1 = csr[j + 4], sc2 = csr[j + 8], sc3 = csr[j + 12];
        float e0 = eexp(als[sc0 * 4 + head] + aldh);
        float e1 = eexp(als[sc1 * 4 + head] + aldh);
        float e2 = eexp(als[sc2 * 4 + head] + aldh);
        float e3 = eexp(als[sc3 * 4 + head] + aldh);
        uint4 u0 = *(const uint4*)&h1[(size_t)sc0 * 128 + c0];
        uint4 u1 = *(const uint4*)&h1[(size_t)sc1 * 128 + c0];
        uint4 u2 = *(const uint4*)&h1[(size_t)sc2 * 128 + c0];
        uint4 u3 = *(const uint4*)&h1[(size_t)sc3 * 128 + c0];
        s += (e0 + e1) + (e2 + e3);
        f32x2 ev0 = {e0, e0}, ev1 = {e1, e1}, ev2 = {e2, e2}, ev3 = {e3, e3};
        a0 += ev0 * unpk2(u0.x); a1 += ev0 * unpk2(u0.y);
        a2 += ev0 * unpk2(u0.z); a3 += ev0 * unpk2(u0.w);
        a0 += ev1 * unpk2(u1.x); a1 += ev1 * unpk2(u1.y);
        a2 += ev1 * unpk2(u1.z); a3 += ev1 * unpk2(u1.w);
        a0 += ev2 * unpk2(u2.x); a1 += ev2 * unpk2(u2.y);
        a2 += ev2 * unpk2(u2.z); a3 += ev2 * unpk2(u2.w);
        a0 += ev3 * unpk2(u3.x); a1 += ev3 * unpk2(u3.y);
        a2 += ev3 * unpk2(u3.z); a3 += ev3 * unpk2(u3.w);
    }
    for (; j < o1; j += 4){
        int sc = csr[j];
        float e = eexp(als[sc * 4 + head] + aldh);
        uint4 u = *(const uint4*)&h1[(size_t)sc * 128 + c0];
        s += e;
        f32x2 ev = {e, e};
        a0 += ev * unpk2(u.x); a1 += ev * unpk2(u.y);
        a2 += ev * unpk2(u.z); a3 += ev * unpk2(u.w);
    }
    float acc[8] = {a0.x, a0.y, a1.x, a1.y, a2.x, a2.y, a3.x, a3.y};
    // reduce over the 4 edge slots (q = lane bits 4..5)
    s += __shfl_xor(s, 16);
    s += __shfl_xor(s, 32);
    #pragma unroll
    for (int i = 0; i < 8; i++){
        acc[i] += __shfl_xor(acc[i], 16);
        acc[i] += __shfl_xor(acc[i], 32);
    }
    if (q == 0){
        float esx = eexp(als[n * 4 + head] + aldh);
        float inv = 1.f / (s + esx + 1e-16f);
        uint4 u = *(const uint4*)&h1[(size_t)n * 128 + c0];
        acc[0] += esx * bf_lo(u.x); acc[1] += esx * bf_hi(u.x);
        acc[2] += esx * bf_lo(u.y); acc[3] += esx * bf_hi(u.y);
        acc[4] += esx * bf_lo(u.z); acc[5] += esx * bf_hi(u.z);
        acc[6] += esx * bf_lo(u.w); acc[7] += esx * bf_hi(u.w);
        float4 bA = *(const float4*)&b1[c0];
        float4 bB = *(const float4*)&b1[c0 + 4];
        u16 pk[8];
        pk[0] = to_bf16(fmaxf(acc[0] * inv + bA.x, 0.f));
        pk[1] = to_bf16(fmaxf(acc[1] * inv + bA.y, 0.f));
        pk[2] = to_bf16(fmaxf(acc[2] * inv + bA.z, 0.f));
        pk[3] = to_bf16(fmaxf(acc[3] * inv + bA.w, 0.f));
        pk[4] = to_bf16(fmaxf(acc[4] * inv + bB.x, 0.f));
        pk[5] = to_bf16(fmaxf(acc[5] * inv + bB.y, 0.f));
        pk[6] = to_bf16(fmaxf(acc[6] * inv + bB.z, 0.f));
        pk[7] = to_bf16(fmaxf(acc[7] * inv + bB.w, 0.f));
        *(uint4*)&outm[(size_t)n * 128 + c0] = *(uint4*)pk;
    }
}

// ------- layer-2 aggregate: single pass, pk-f32x2 accum -------
__global__ __launch_bounds__(256) void gat_agg2(const int* __restrict__ off,
                                                const u16* __restrict__ csr,
                                                const u16* __restrict__ h2,
                                                const float* __restrict__ als,
                                                const float* __restrict__ ald,
                                                const float* __restrict__ b2,
                                                void* __restrict__ outv, int N,
                                                const int* __restrict__ flag){
    int lane = threadIdx.x & 63;
    int n = blockIdx.x * 4 + (threadIdx.x >> 6);
    if (n >= N) return;
    int o0 = off[n], o1 = off[n + 1];
    int oc = lane >> 3, ol = lane & 7;   // oc: edge slot (mod 8), ol: column group
    int c0 = ol * 8;
    float aldn = ald[n];
    f32x2 a0 = {0.f, 0.f}, a1 = {0.f, 0.f}, a2 = {0.f, 0.f}, a3 = {0.f, 0.f};
    float s = 0.f;
    int j = o0 + oc;
    for (; j + 8 < o1; j += 16){
        int sc0 = csr[j], sc1 = csr[j + 8];
        float e0 = eexp(als[sc0] + aldn);
        float e1 = eexp(als[sc1] + aldn);
        uint4 u0 = *(const uint4*)&h2[(size_t)sc0 * 64 + c0];
        uint4 u1 = *(const uint4*)&h2[(size_t)sc1 * 64 + c0];
        s += e0 + e1;
        f32x2 ev0 = {e0, e0}, ev1 = {e1, e1};
        a0 += ev0 * unpk2(u0.x); a1 += ev0 * unpk2(u0.y);
        a2 += ev0 * unpk2(u0.z); a3 += ev0 * unpk2(u0.w);
        a0 += ev1 * unpk2(u1.x); a1 += ev1 * unpk2(u1.y);
        a2 += ev1 * unpk2(u1.z); a3 += ev1 * unpk2(u1.w);
    }
    if (j < o1){
        int sc = csr[j];
        float e = eexp(als[sc] + aldn);
        uint4 u = *(const uint4*)&h2[(size_t)sc * 64 + c0];
        s += e;
        f32x2 ev = {e, e};
        a0 += ev * unpk2(u.x); a1 += ev * unpk2(u.y);
        a2 += ev * unpk2(u.z); a3 += ev * unpk2(u.w);
    }
    float acc[8] = {a0.x, a0.y, a1.x, a1.y, a2.x, a2.y, a3.x, a3.y};
    // reduce over the 8 edge slots (oc = lane bits 3..5)
    s += __shfl_xor(s, 8);
    s += __shfl_xor(s, 16);
    s += __shfl_xor(s, 32);
    #pragma unroll
    for (int i = 0; i < 8; i++){
        acc[i] += __shfl_xor(acc[i], 8);
        acc[i] += __shfl_xor(acc[i], 16);
        acc[i] += __shfl_xor(acc[i], 32);
    }
    if (oc == 0){
        float esx = eexp(als[n] + aldn);
        float inv = 1.f / (s + esx + 1e-16f);
        uint4 u = *(const uint4*)&h2[(size_t)n * 64 + c0];
        acc[0] += esx * bf_lo(u.x); acc[1] += esx * bf_hi(u.x);
        acc[2] += esx * bf_lo(u.y); acc[3] += esx * bf_hi(u.y);
        acc[4] += esx * bf_lo(u.z); acc[5] += esx * bf_hi(u.z);
        acc[6] += esx * bf_lo(u.w); acc[7] += esx * bf_hi(u.w);
        float4 bA = *(const float4*)&b2[c0];
        float4 bB = *(const float4*)&b2[c0 + 4];
        float r[8];
        r[0] = acc[0] * inv + bA.x; r[1] = acc[1] * inv + bA.y;
        r[2] = acc[2] * inv + bA.z; r[3] = acc[3] * inv + bA.w;
        r[4] = acc[4] * inv + bB.x; r[5] = acc[5] * inv + bB.y;
        r[6] = acc[6] * inv + bB.z; r[7] = acc[7] * inv + bB.w;
        if (*flag){
            u16 pk[8];
            #pragma unroll
            for (int i = 0; i < 8; i++) pk[i] = to_bf16(r[i]);
            *(uint4*)&((u16*)outv)[(size_t)n * 64 + c0] = *(uint4*)pk;
        } else {
            float* op = &((float*)outv)[(size_t)n * 64 + c0];
            *(float4*)op = make_float4(r[0], r[1], r[2], r[3]);
            *(float4*)(op + 4) = make_float4(r[4], r[5], r[6], r[7]);
        }
    }
}

extern "C" void kernel_launch(void* const* d_in, const int* in_sizes, int n_in,
                              void* d_out, int out_size, void* d_ws, size_t ws_size,
                              hipStream_t stream){
    const int* ei  = (const int*)d_in[1];
    const int N = in_sizes[0] / 128;
    const int E = in_sizes[1] / 2;
    const int* src = ei;
    const int* dst = ei + E;
    const int NBIN = (N + 511) >> 9;         // <=128 while N<=65536
    const int chE  = (E + NS - 1) / NS;

    char* w = (char*)d_ws;
    auto alloc = [&](size_t bytes){ char* p = w; w += (bytes + 255) & ~(size_t)255; return p; };
    int*   flag  = (int*)  alloc(4);
    u16*   cnt   = (u16*)  alloc((size_t)NS * NBIN * 2);
    u32*   Sbin  = (u32*)  alloc((size_t)(NBIN + 1) * 4);
    u32*   bucket= (u32*)  alloc((size_t)E * 4);
    int*   off   = (int*)  alloc((size_t)(N + 1) * 4);
    u16*   csr   = (u16*)  alloc((size_t)E * 2);
    u16*   W1t   = (u16*)  alloc(128 * 128 * 2);
    u16*   W2t   = (u16*)  alloc(64 * 128 * 2);
    float* as1f  = (float*)alloc(128 * 4);
    float* ad1f  = (float*)alloc(128 * 4);
    float* b1f   = (float*)alloc(128 * 4);
    float* as2f  = (float*)alloc(64 * 4);
    float* ad2f  = (float*)alloc(64 * 4);
    float* b2f   = (float*)alloc(64 * 4);
    u16*   Xb    = (u16*)  alloc((size_t)N * 128 * 2);
    u16*   h1b   = (u16*)  alloc((size_t)N * 128 * 2);
    u16*   hmidb = (u16*)  alloc((size_t)N * 128 * 2);
    u16*   h2b   = (u16*)  alloc((size_t)N * 64 * 2);
    float* als1  = (float*)alloc((size_t)N * 4 * 4);
    float* ald1  = (float*)alloc((size_t)N * 4 * 4);
    float* als2  = als1;
    float* ald2  = ald1;

    HistCvtArgs k1;
    k1.dst = dst; k1.src = src; k1.E = E; k1.chE = chE; k1.cnt = cnt; k1.NBIN = NBIN;
    k1.xin = d_in[0]; k1.Xb = Xb; k1.nx = N * 128;
    k1.W1 = d_in[2]; k1.W2 = d_in[6]; k1.W1t = W1t; k1.W2t = W2t;
    const void* vin[6]  = {d_in[3], d_in[4], d_in[5], d_in[7], d_in[8], d_in[9]};
    float* vout[6] = {as1f, ad1f, b1f, as2f, ad2f, b2f};
    for (int s = 0; s < 6; s++){ k1.vin[s] = vin[s]; k1.vout[s] = vout[s]; }
    k1.flag = flag;
    int cvt_total = N * 128 + 128 * 128 + 64 * 128 + 576;
    hist_cvt<<<NS + (cvt_total + 255) / 256, 256, 0, stream>>>(k1);

    BucketGemmArgs k3;
    k3.dst = dst; k3.src = src; k3.E = E; k3.chE = chE; k3.cnt = cnt; k3.NBIN = NBIN;
    k3.Sbin = Sbin;
    k3.bucket = bucket;
    k3.Xb = Xb; k3.W1t = W1t; k3.HB = h1b;
    k3.a_s = as1f; k3.a_d = ad1f; k3.al_s = als1; k3.al_d = ald1;
    k3.N = N;
    bucket_gemm<<<NS + (N + 63) / 64, 256, 0, stream>>>(k3);

    bin_csr<<<NBIN, 256, 0, stream>>>(Sbin, bucket, off, csr, N, NBIN);

    gat_agg1<<<(N + 3) / 4, 256, 0, stream>>>(off, csr, h1b, als1, ald1, b1f, hmidb, N);

    gemm2_logits<<<(N + 63) / 64, 256, 0, stream>>>(hmidb, W2t, h2b, as2f, ad2f, als2, ald2, N);

    gat_agg2<<<(N + 3) / 4, 256, 0, stream>>>(off, csr, h2b, als2, ald2, b2f, d_out, N, flag);
}